// Round 18
// baseline (467.119 us; speedup 1.0000x reference)
//
#include <hip/hip_runtime.h>
#include <math.h>

#define CCH 48
#define NST 16
#define VOX (64*64*64)
#define LOG2E 1.44269504088896340736f

typedef __attribute__((ext_vector_type(8))) short bf16x8_t;
typedef __attribute__((ext_vector_type(4))) float f32x4_t;
typedef unsigned short ushort_t;

__device__ __forceinline__ float softplus_f(float s) {
    return fmaxf(s, 0.f) + log1pf(__expf(-fabsf(s)));
}

__device__ __forceinline__ ushort_t f2bf(float f) {
    unsigned u = __float_as_uint(f);
    unsigned r = (u + 0x7FFF + ((u >> 16) & 1)) >> 16;
    return (ushort_t)r;
}

// Fusable dpp-add: old = src, bound_ctrl = false. All lanes valid under the
// xor-involution controls used below, so the backend can emit a single
// v_add_f32 with a dpp modifier (r15's old=0/bound_ctrl=true form emitted
// mov + dpp-mov + add, ~3x the instructions).
template<int CTRL>
__device__ __forceinline__ float dpp_add(float x) {
    int xi = __float_as_int(x);
    int v = __builtin_amdgcn_update_dpp(xi, xi, CTRL, 0xF, 0xF, false);
    return x + __int_as_float(v);
}

__global__ __launch_bounds__(256) void k_transpose_in(const float* __restrict__ x,
                                                      float* __restrict__ xt) {
    __shared__ float tile[CCH * 65];
    int v0 = blockIdx.x * 64;
    int t = threadIdx.x;
#pragma unroll
    for (int i = 0; i < 12; ++i) {
        int idx = t + i * 256;
        int c = idx >> 6, v = idx & 63;
        tile[c * 65 + v] = x[c * VOX + v0 + v];
    }
    __syncthreads();
#pragma unroll
    for (int i = 0; i < 12; ++i) {
        int idx = t + i * 256;
        int v = idx / CCH, c = idx - v * CCH;
        xt[(v0 + v) * CCH + c] = tile[c * 65 + v];
    }
}

__global__ __launch_bounds__(256) void k_transpose_out(const float* __restrict__ yws,
                                                       float* __restrict__ out) {
    __shared__ float tile[CCH * 65];
    int v0 = blockIdx.x * 64;
    int t = threadIdx.x;
#pragma unroll
    for (int i = 0; i < 12; ++i) {
        int idx = t + i * 256;
        int v = idx / CCH, c = idx - v * CCH;
        tile[c * 65 + v] = yws[(v0 + v) * CCH + c];
    }
    __syncthreads();
#pragma unroll
    for (int i = 0; i < 12; ++i) {
        int idx = t + i * 256;
        int c = idx >> 6, v = idx & 63;
        out[c * VOX + v0 + v] = tile[c * 65 + v];
    }
}

// LDS layout (float offsets):
#define OFF_XS    0        // 3072  xs fp32 [l][48]
#define OFF_XB    3072     // 2304  xs bf16 [l][72] (u16; k 48..63 zero pad)
#define OFF_WB16  5376     // 2880  W bf16 [80][72] (rows 0..47 dt^T, 48..63 B^T, 64..79 C^T)
#define OFF_DTS   8256     // 3264  dtsT[c*68+l]
#define OFF_UX    11520    // 3264  uxT[c*68+l]
#define OFF_BC    14784    // 1088  BcsT[n*68+l]
#define OFF_CC    15872    // 1088  CcsT[n*68+l]
#define OFF_YS    3072     // 3072  ys[l*48+c] (aliases XB+WB16 after MFMA phase)
#define SMEM_FLOATS 16960  // 67,840 B -> 2 blocks/CU

// Ledger (empirical, this kernel):
//  launch_bounds: arg2=6 -> RA cap 40 VGPR. arg2=4/2 -> 64 VGPR -> crosses
//    m69 waves/CU halving -> 1 block/CU, 1.9x latency (r8/r9). KEEP (768,6).
//  r15 (MFMA proj): 125us, VALUBusy 79%, MfmaUtil 0.9%, conflicts 3.1e6.
//    Emitted-instr bloat in scan loop: __expf = mul+exp; dpp_add(old=0,
//    bound_ctrl=1) = mov+dppmov+add. This round: exp2f + fusable dpp.
//  Cross-lane: xor-involution dpp (0xB1/0x4E/0x141) 8-lane reduce OK (r12).
//    ror {1,2,4} 8-lane WRONG (r10). MFMA D-layout: col=lane&15,
//    row=(lane>>4)*4+reg (m89-verified).
__global__ __launch_bounds__(768, 6) void k_scan(
    const float* __restrict__ xt, float* __restrict__ yws,
    const float* __restrict__ A_log, const float* __restrict__ W_dt,
    const float* __restrict__ b_dt, const float* __restrict__ W_B,
    const float* __restrict__ W_C, const float* __restrict__ D_skip,
    int dir, int stride_v, int accumulate)
{
    __shared__ __align__(16) float smem[SMEM_FLOATS];
    float* xs   = smem + OFF_XS;
    float* dtsT = smem + OFF_DTS;
    float* uxT  = smem + OFF_UX;
    float* BcsT = smem + OFF_BC;
    float* CcsT = smem + OFF_CC;
    float* ys   = smem + OFF_YS;
    ushort_t* xb = (ushort_t*)(smem + OFF_XB);
    ushort_t* wb = (ushort_t*)(smem + OFF_WB16);

    int t = threadIdx.x;
    int lid = blockIdx.x;
    int a = lid >> 6, b = lid & 63;
    int vbase;
    if (dir == 0) vbase = lid;                 // step stride 4096 (along D)
    else if (dir == 1) vbase = a * 4096 + b;   // step stride 64   (along H)
    else vbase = a * 4096 + b * 64;            // step stride 1    (along W)

    const float* wdt_g = W_dt + dir * CCH * CCH;
    const float* wB_g  = W_B + dir * CCH * NST;
    const float* wC_g  = W_C + dir * CCH * NST;

    // ---- stage line of x: fp32 + bf16 copies ----
    {
        int q = t % 12, l = t / 12;
        float4 v = *(const float4*)&xt[(vbase + l * stride_v) * CCH + 4 * q];
        *(float4*)&xs[l * CCH + 4 * q] = v;
        unsigned p0 = (unsigned)f2bf(v.x) | ((unsigned)f2bf(v.y) << 16);
        unsigned p1 = (unsigned)f2bf(v.z) | ((unsigned)f2bf(v.w) << 16);
        unsigned* d = (unsigned*)&xb[l * 72 + 4 * q];
        d[0] = p0; d[1] = p1;
    }
    // ---- stage weights bf16, transposed: wb[row][k], row = output index ----
    for (int idx = t; idx < 3840; idx += 768) {
        float v; int row, k;
        if (idx < 2304)      { k = idx / 48;       row = idx % 48;        v = wdt_g[idx]; }
        else if (idx < 3072) { int j = idx - 2304; k = j >> 4; row = 48 + (j & 15); v = wB_g[j]; }
        else                 { int j = idx - 3072; k = j >> 4; row = 64 + (j & 15); v = wC_g[j]; }
        wb[row * 72 + k] = f2bf(v);
    }
    // ---- zero K-pads (k = 48..63) ----
    for (int i = t; i < 80 * 16; i += 768) wb[(i >> 4) * 72 + 48 + (i & 15)] = 0;
    for (int i = t; i < 64 * 16; i += 768) xb[(i >> 4) * 72 + 48 + (i & 15)] = 0;
    __syncthreads();

    // ---- MFMA projections: O[80][64] = W(80x48) * x^T(48x64), bf16 in fp32 out.
    {
        int w = t >> 6, lane = t & 63;
        if (w < 10) {
            int r16 = lane & 15, g = lane >> 4;
#pragma unroll
            for (int tt = 0; tt < 2; ++tt) {
                int tile = w * 2 + tt;
                int tm = tile >> 2, tn = tile & 3;
                const ushort_t* ap = &wb[(tm * 16 + r16) * 72 + g * 8];
                const ushort_t* bp = &xb[(tn * 16 + r16) * 72 + g * 8];
                bf16x8_t A0 = *(const bf16x8_t*)ap;
                bf16x8_t A1 = *(const bf16x8_t*)(ap + 32);
                bf16x8_t B0 = *(const bf16x8_t*)bp;
                bf16x8_t B1 = *(const bf16x8_t*)(bp + 32);
                f32x4_t acc = {0.f, 0.f, 0.f, 0.f};
                acc = __builtin_amdgcn_mfma_f32_16x16x32_bf16(A0, B0, acc, 0, 0, 0);
                acc = __builtin_amdgcn_mfma_f32_16x16x32_bf16(A1, B1, acc, 0, 0, 0);
                int col = tn * 16 + r16;
                float* outp;
                if (tm < 3)       outp = &dtsT[(tm * 16 + g * 4) * 68 + col];
                else if (tm == 3) outp = &BcsT[(g * 4) * 68 + col];
                else              outp = &CcsT[(g * 4) * 68 + col];
                outp[0 * 68] = acc[0];
                outp[1 * 68] = acc[1];
                outp[2 * 68] = acc[2];
                outp[3 * 68] = acc[3];
            }
        }
    }
    __syncthreads();

    // ---- pointwise: bias + softplus on dt; ux = dt * x ----
    {
        int c = t % CCH, l0 = t / CCH;   // l0 0..15, owns l = 4*l0..4*l0+3
        float bias = b_dt[dir * CCH + c];
        float4 dv = *(const float4*)&dtsT[c * 68 + 4 * l0];
        float4 dtv, uxv;
        dtv.x = softplus_f(dv.x + bias); uxv.x = dtv.x * xs[(4 * l0 + 0) * CCH + c];
        dtv.y = softplus_f(dv.y + bias); uxv.y = dtv.y * xs[(4 * l0 + 1) * CCH + c];
        dtv.z = softplus_f(dv.z + bias); uxv.z = dtv.z * xs[(4 * l0 + 2) * CCH + c];
        dtv.w = softplus_f(dv.w + bias); uxv.w = dtv.w * xs[(4 * l0 + 3) * CCH + c];
        *(float4*)&dtsT[c * 68 + 4 * l0] = dtv;
        *(float4*)&uxT[c * 68 + 4 * l0]  = uxv;
    }
    __syncthreads();

    // ---- sequential scan: 384 threads, TWO states (c,nh) and (c,nh+8) ----
    // exp2 path: a' = -exp(A_log)*log2e precomputed -> exp2f() emits a single
    // v_exp_f32 (base-2 HW instr), vs __expf's v_mul+v_exp.
    if (t < 384) {
        int cc = t >> 3, nh = t & 7;
        float a0 = -expf(A_log[dir * CCH * NST + cc * NST + nh]) * LOG2E;
        float a1 = -expf(A_log[dir * CCH * NST + cc * NST + nh + 8]) * LOG2E;
        const float4* dt4 = (const float4*)&dtsT[cc * 68];
        const float4* ux4 = (const float4*)&uxT[cc * 68];
        const float4* B4a = (const float4*)&BcsT[nh * 68];
        const float4* B4b = (const float4*)&BcsT[(nh + 8) * 68];
        const float4* C4a = (const float4*)&CcsT[nh * 68];
        const float4* C4b = (const float4*)&CcsT[(nh + 8) * 68];
        float h0 = 0.f, h1 = 0.f;

#define STEP(COMP, LIDX)                                                    \
        {                                                                   \
            float e0 = exp2f(dtv.COMP * a0);                                \
            float e1 = exp2f(dtv.COMP * a1);                                \
            h0 = fmaf(e0, h0, uxv.COMP * Bva.COMP);                         \
            h1 = fmaf(e1, h1, uxv.COMP * Bvb.COMP);                         \
            float p = fmaf(h1, Cvb.COMP, h0 * Cva.COMP);                    \
            p = dpp_add<0xB1>(p);                                           \
            p = dpp_add<0x4E>(p);                                           \
            p = dpp_add<0x141>(p);                                          \
            if (nh == 0) ys[(LIDX) * CCH + cc] = p;                         \
        }

#pragma unroll
        for (int l4 = 0; l4 < 16; ++l4) {
            float4 dtv = dt4[l4];
            float4 uxv = ux4[l4];
            float4 Bva = B4a[l4];
            float4 Bvb = B4b[l4];
            float4 Cva = C4a[l4];
            float4 Cvb = C4b[l4];
            STEP(x, l4 * 4 + 0)
            STEP(y, l4 * 4 + 1)
            STEP(z, l4 * 4 + 2)
            STEP(w, l4 * 4 + 3)
        }
#undef STEP
    }
    __syncthreads();

    // ---- add skip term and write/accumulate to yws ----
    {
        int q = t % 12, l = t / 12;
        float4 yv = *(const float4*)&ys[l * CCH + 4 * q];
        float4 xv = *(const float4*)&xs[l * CCH + 4 * q];
        float4 dv = *(const float4*)&D_skip[dir * CCH + 4 * q];
        yv.x = fmaf(dv.x, xv.x, yv.x);
        yv.y = fmaf(dv.y, xv.y, yv.y);
        yv.z = fmaf(dv.z, xv.z, yv.z);
        yv.w = fmaf(dv.w, xv.w, yv.w);
        float* gp = &yws[(vbase + l * stride_v) * CCH + 4 * q];
        if (accumulate) {
            float4 old = *(const float4*)gp;
            yv.x += old.x; yv.y += old.y; yv.z += old.z; yv.w += old.w;
        }
        *(float4*)gp = yv;
    }
}

extern "C" void kernel_launch(void* const* d_in, const int* in_sizes, int n_in,
                              void* d_out, int out_size, void* d_ws, size_t ws_size,
                              hipStream_t stream) {
    const float* x      = (const float*)d_in[0];
    const float* A_log  = (const float*)d_in[1];
    const float* W_dt   = (const float*)d_in[2];
    const float* b_dt   = (const float*)d_in[3];
    const float* W_B    = (const float*)d_in[4];
    const float* W_C    = (const float*)d_in[5];
    const float* D_skip = (const float*)d_in[6];
    float* out = (float*)d_out;

    float* xt  = (float*)d_ws;
    float* yws = xt + (size_t)VOX * CCH;

    k_transpose_in<<<VOX / 64, 256, 0, stream>>>(x, xt);
    k_scan<<<4096, 768, 0, stream>>>(xt, yws, A_log, W_dt, b_dt, W_B, W_C, D_skip, 0, 4096, 0);
    k_scan<<<4096, 768, 0, stream>>>(xt, yws, A_log, W_dt, b_dt, W_B, W_C, D_skip, 1, 64, 1);
    k_scan<<<4096, 768, 0, stream>>>(xt, yws, A_log, W_dt, b_dt, W_B, W_C, D_skip, 2, 1, 1);
    k_transpose_out<<<VOX / 64, 256, 0, stream>>>(yws, out);
}

// Round 19
// 347.067 us; speedup vs baseline: 1.3459x; 1.3459x over previous
//
#include <hip/hip_runtime.h>
#include <math.h>

#define CCH 48
#define NST 16
#define VOX (64*64*64)
#define LOG2E 1.44269504088896340736f

typedef __attribute__((ext_vector_type(8))) short bf16x8_t;
typedef __attribute__((ext_vector_type(4))) float f32x4_t;
typedef unsigned short ushort_t;

__device__ __forceinline__ float softplus_f(float s) {
    return fmaxf(s, 0.f) + log1pf(__expf(-fabsf(s)));
}

__device__ __forceinline__ ushort_t f2bf(float f) {
    unsigned u = __float_as_uint(f);
    unsigned r = (u + 0x7FFF + ((u >> 16) & 1)) >> 16;
    return (ushort_t)r;
}

// r15-proven dpp_add form (old=0, bound_ctrl=true). The r18 "fusable" variant
// was bundled with libm exp2f and the pair regressed; reverting both, then
// re-isolating one change at a time.
template<int CTRL>
__device__ __forceinline__ float dpp_add(float x) {
    int v = __builtin_amdgcn_update_dpp(0, __float_as_int(x), CTRL, 0xF, 0xF, true);
    return x + __int_as_float(v);
}

__global__ __launch_bounds__(256) void k_transpose_in(const float* __restrict__ x,
                                                      float* __restrict__ xt) {
    __shared__ float tile[CCH * 65];
    int v0 = blockIdx.x * 64;
    int t = threadIdx.x;
#pragma unroll
    for (int i = 0; i < 12; ++i) {
        int idx = t + i * 256;
        int c = idx >> 6, v = idx & 63;
        tile[c * 65 + v] = x[c * VOX + v0 + v];
    }
    __syncthreads();
#pragma unroll
    for (int i = 0; i < 12; ++i) {
        int idx = t + i * 256;
        int v = idx / CCH, c = idx - v * CCH;
        xt[(v0 + v) * CCH + c] = tile[c * 65 + v];
    }
}

__global__ __launch_bounds__(256) void k_transpose_out(const float* __restrict__ yws,
                                                       float* __restrict__ out) {
    __shared__ float tile[CCH * 65];
    int v0 = blockIdx.x * 64;
    int t = threadIdx.x;
#pragma unroll
    for (int i = 0; i < 12; ++i) {
        int idx = t + i * 256;
        int v = idx / CCH, c = idx - v * CCH;
        tile[c * 65 + v] = yws[(v0 + v) * CCH + c];
    }
    __syncthreads();
#pragma unroll
    for (int i = 0; i < 12; ++i) {
        int idx = t + i * 256;
        int c = idx >> 6, v = idx & 63;
        out[c * VOX + v0 + v] = tile[c * 65 + v];
    }
}

// LDS layout (float offsets):
#define OFF_XS    0        // 3072  xs fp32 [l][48]
#define OFF_XB    3072     // 2304  xs bf16 [l][72] (u16; k 48..63 zero pad)
#define OFF_WB16  5376     // 2880  W bf16 [80][72] (rows 0..47 dt^T, 48..63 B^T, 64..79 C^T)
#define OFF_DTS   8256     // 3264  dtsT[c*68+l]
#define OFF_UX    11520    // 3264  uxT[c*68+l]
#define OFF_BC    14784    // 1088  BcsT[n*68+l]
#define OFF_CC    15872    // 1088  CcsT[n*68+l]
#define OFF_YS    3072     // 3072  ys[l*48+c] (aliases XB+WB16 after MFMA phase)
#define SMEM_FLOATS 16960  // 67,840 B -> 2 blocks/CU

// Ledger (empirical, this kernel):
//  launch_bounds: arg2=6 -> RA cap 40 VGPR. arg2=4/2 -> 64 VGPR -> crosses
//    m69 waves/CU halving -> 1 block/CU, 1.9x latency (r8/r9). KEEP (768,6).
//  r15 (MFMA proj, __expf, dpp old=0): 125us, VALUBusy 79%, MfmaUtil 0.9%.
//  r18: libm exp2f = REGRESSION 125->163us. Without fast-math, llvm.exp2.f32
//    lowers to range-check+scale+select (~6-8 instrs), NOT bare v_exp_f32.
//    __builtin_amdgcn_exp2f is the raw HW instr -> this round's single change.
//  Cross-lane: xor-involution dpp (0xB1/0x4E/0x141) 8-lane reduce OK (r12).
//    ror {1,2,4} 8-lane WRONG (r10). MFMA D-layout: col=lane&15,
//    row=(lane>>4)*4+reg (m89-verified).
__global__ __launch_bounds__(768, 6) void k_scan(
    const float* __restrict__ xt, float* __restrict__ yws,
    const float* __restrict__ A_log, const float* __restrict__ W_dt,
    const float* __restrict__ b_dt, const float* __restrict__ W_B,
    const float* __restrict__ W_C, const float* __restrict__ D_skip,
    int dir, int stride_v, int accumulate)
{
    __shared__ __align__(16) float smem[SMEM_FLOATS];
    float* xs   = smem + OFF_XS;
    float* dtsT = smem + OFF_DTS;
    float* uxT  = smem + OFF_UX;
    float* BcsT = smem + OFF_BC;
    float* CcsT = smem + OFF_CC;
    float* ys   = smem + OFF_YS;
    ushort_t* xb = (ushort_t*)(smem + OFF_XB);
    ushort_t* wb = (ushort_t*)(smem + OFF_WB16);

    int t = threadIdx.x;
    int lid = blockIdx.x;
    int a = lid >> 6, b = lid & 63;
    int vbase;
    if (dir == 0) vbase = lid;                 // step stride 4096 (along D)
    else if (dir == 1) vbase = a * 4096 + b;   // step stride 64   (along H)
    else vbase = a * 4096 + b * 64;            // step stride 1    (along W)

    const float* wdt_g = W_dt + dir * CCH * CCH;
    const float* wB_g  = W_B + dir * CCH * NST;
    const float* wC_g  = W_C + dir * CCH * NST;

    // ---- stage line of x: fp32 + bf16 copies ----
    {
        int q = t % 12, l = t / 12;
        float4 v = *(const float4*)&xt[(vbase + l * stride_v) * CCH + 4 * q];
        *(float4*)&xs[l * CCH + 4 * q] = v;
        unsigned p0 = (unsigned)f2bf(v.x) | ((unsigned)f2bf(v.y) << 16);
        unsigned p1 = (unsigned)f2bf(v.z) | ((unsigned)f2bf(v.w) << 16);
        unsigned* d = (unsigned*)&xb[l * 72 + 4 * q];
        d[0] = p0; d[1] = p1;
    }
    // ---- stage weights bf16, transposed: wb[row][k], row = output index ----
    for (int idx = t; idx < 3840; idx += 768) {
        float v; int row, k;
        if (idx < 2304)      { k = idx / 48;       row = idx % 48;        v = wdt_g[idx]; }
        else if (idx < 3072) { int j = idx - 2304; k = j >> 4; row = 48 + (j & 15); v = wB_g[j]; }
        else                 { int j = idx - 3072; k = j >> 4; row = 64 + (j & 15); v = wC_g[j]; }
        wb[row * 72 + k] = f2bf(v);
    }
    // ---- zero K-pads (k = 48..63) ----
    for (int i = t; i < 80 * 16; i += 768) wb[(i >> 4) * 72 + 48 + (i & 15)] = 0;
    for (int i = t; i < 64 * 16; i += 768) xb[(i >> 4) * 72 + 48 + (i & 15)] = 0;
    __syncthreads();

    // ---- MFMA projections: O[80][64] = W(80x48) * x^T(48x64), bf16 in fp32 out.
    {
        int w = t >> 6, lane = t & 63;
        if (w < 10) {
            int r16 = lane & 15, g = lane >> 4;
#pragma unroll
            for (int tt = 0; tt < 2; ++tt) {
                int tile = w * 2 + tt;
                int tm = tile >> 2, tn = tile & 3;
                const ushort_t* ap = &wb[(tm * 16 + r16) * 72 + g * 8];
                const ushort_t* bp = &xb[(tn * 16 + r16) * 72 + g * 8];
                bf16x8_t A0 = *(const bf16x8_t*)ap;
                bf16x8_t A1 = *(const bf16x8_t*)(ap + 32);
                bf16x8_t B0 = *(const bf16x8_t*)bp;
                bf16x8_t B1 = *(const bf16x8_t*)(bp + 32);
                f32x4_t acc = {0.f, 0.f, 0.f, 0.f};
                acc = __builtin_amdgcn_mfma_f32_16x16x32_bf16(A0, B0, acc, 0, 0, 0);
                acc = __builtin_amdgcn_mfma_f32_16x16x32_bf16(A1, B1, acc, 0, 0, 0);
                int col = tn * 16 + r16;
                float* outp;
                if (tm < 3)       outp = &dtsT[(tm * 16 + g * 4) * 68 + col];
                else if (tm == 3) outp = &BcsT[(g * 4) * 68 + col];
                else              outp = &CcsT[(g * 4) * 68 + col];
                outp[0 * 68] = acc[0];
                outp[1 * 68] = acc[1];
                outp[2 * 68] = acc[2];
                outp[3 * 68] = acc[3];
            }
        }
    }
    __syncthreads();

    // ---- pointwise: bias + softplus on dt; ux = dt * x ----
    {
        int c = t % CCH, l0 = t / CCH;   // l0 0..15, owns l = 4*l0..4*l0+3
        float bias = b_dt[dir * CCH + c];
        float4 dv = *(const float4*)&dtsT[c * 68 + 4 * l0];
        float4 dtv, uxv;
        dtv.x = softplus_f(dv.x + bias); uxv.x = dtv.x * xs[(4 * l0 + 0) * CCH + c];
        dtv.y = softplus_f(dv.y + bias); uxv.y = dtv.y * xs[(4 * l0 + 1) * CCH + c];
        dtv.z = softplus_f(dv.z + bias); uxv.z = dtv.z * xs[(4 * l0 + 2) * CCH + c];
        dtv.w = softplus_f(dv.w + bias); uxv.w = dtv.w * xs[(4 * l0 + 3) * CCH + c];
        *(float4*)&dtsT[c * 68 + 4 * l0] = dtv;
        *(float4*)&uxT[c * 68 + 4 * l0]  = uxv;
    }
    __syncthreads();

    // ---- sequential scan: 384 threads, TWO states (c,nh) and (c,nh+8) ----
    // a' = -exp(A_log)*log2e hoisted; __builtin_amdgcn_exp2f = bare v_exp_f32
    // (raw llvm.amdgcn.exp2 intrinsic, no precise-path fixup).
    if (t < 384) {
        int cc = t >> 3, nh = t & 7;
        float a0 = -expf(A_log[dir * CCH * NST + cc * NST + nh]) * LOG2E;
        float a1 = -expf(A_log[dir * CCH * NST + cc * NST + nh + 8]) * LOG2E;
        const float4* dt4 = (const float4*)&dtsT[cc * 68];
        const float4* ux4 = (const float4*)&uxT[cc * 68];
        const float4* B4a = (const float4*)&BcsT[nh * 68];
        const float4* B4b = (const float4*)&BcsT[(nh + 8) * 68];
        const float4* C4a = (const float4*)&CcsT[nh * 68];
        const float4* C4b = (const float4*)&CcsT[(nh + 8) * 68];
        float h0 = 0.f, h1 = 0.f;

#define STEP(COMP, LIDX)                                                    \
        {                                                                   \
            float e0 = __builtin_amdgcn_exp2f(dtv.COMP * a0);               \
            float e1 = __builtin_amdgcn_exp2f(dtv.COMP * a1);               \
            h0 = fmaf(e0, h0, uxv.COMP * Bva.COMP);                         \
            h1 = fmaf(e1, h1, uxv.COMP * Bvb.COMP);                         \
            float p = fmaf(h1, Cvb.COMP, h0 * Cva.COMP);                    \
            p = dpp_add<0xB1>(p);                                           \
            p = dpp_add<0x4E>(p);                                           \
            p = dpp_add<0x141>(p);                                          \
            if (nh == 0) ys[(LIDX) * CCH + cc] = p;                         \
        }

#pragma unroll
        for (int l4 = 0; l4 < 16; ++l4) {
            float4 dtv = dt4[l4];
            float4 uxv = ux4[l4];
            float4 Bva = B4a[l4];
            float4 Bvb = B4b[l4];
            float4 Cva = C4a[l4];
            float4 Cvb = C4b[l4];
            STEP(x, l4 * 4 + 0)
            STEP(y, l4 * 4 + 1)
            STEP(z, l4 * 4 + 2)
            STEP(w, l4 * 4 + 3)
        }
#undef STEP
    }
    __syncthreads();

    // ---- add skip term and write/accumulate to yws ----
    {
        int q = t % 12, l = t / 12;
        float4 yv = *(const float4*)&ys[l * CCH + 4 * q];
        float4 xv = *(const float4*)&xs[l * CCH + 4 * q];
        float4 dv = *(const float4*)&D_skip[dir * CCH + 4 * q];
        yv.x = fmaf(dv.x, xv.x, yv.x);
        yv.y = fmaf(dv.y, xv.y, yv.y);
        yv.z = fmaf(dv.z, xv.z, yv.z);
        yv.w = fmaf(dv.w, xv.w, yv.w);
        float* gp = &yws[(vbase + l * stride_v) * CCH + 4 * q];
        if (accumulate) {
            float4 old = *(const float4*)gp;
            yv.x += old.x; yv.y += old.y; yv.z += old.z; yv.w += old.w;
        }
        *(float4*)gp = yv;
    }
}

extern "C" void kernel_launch(void* const* d_in, const int* in_sizes, int n_in,
                              void* d_out, int out_size, void* d_ws, size_t ws_size,
                              hipStream_t stream) {
    const float* x      = (const float*)d_in[0];
    const float* A_log  = (const float*)d_in[1];
    const float* W_dt   = (const float*)d_in[2];
    const float* b_dt   = (const float*)d_in[3];
    const float* W_B    = (const float*)d_in[4];
    const float* W_C    = (const float*)d_in[5];
    const float* D_skip = (const float*)d_in[6];
    float* out = (float*)d_out;

    float* xt  = (float*)d_ws;
    float* yws = xt + (size_t)VOX * CCH;

    k_transpose_in<<<VOX / 64, 256, 0, stream>>>(x, xt);
    k_scan<<<4096, 768, 0, stream>>>(xt, yws, A_log, W_dt, b_dt, W_B, W_C, D_skip, 0, 4096, 0);
    k_scan<<<4096, 768, 0, stream>>>(xt, yws, A_log, W_dt, b_dt, W_B, W_C, D_skip, 1, 64, 1);
    k_scan<<<4096, 768, 0, stream>>>(xt, yws, A_log, W_dt, b_dt, W_B, W_C, D_skip, 2, 1, 1);
    k_transpose_out<<<VOX / 64, 256, 0, stream>>>(yws, out);
}